// Round 1
// baseline (336.307 us; speedup 1.0000x reference)
//
#include <hip/hip_runtime.h>

// GAT attention weights (heads=1) for two block-diagonal graphs.
// Output = softmax-by-dst of leakyrelu(a_s[src]+a_d[dst]) over N*N edges.
//
// Pipeline:
//  K1: ws = W@att_src, wd = W@att_dst            (256 floats each)
//  K2: a_s[i] = x[i]·ws, a_d[i] = x[i]·wd         (8192 nodes, wave/node)
//  K3: per-edge exp(lrelu(...)) -> per-block LDS segment sums -> partials
//  K4a/K4b: tree-reduce partials -> inv_denom[8192]
//  K5: per-edge alpha = exp(lrelu(...)) * inv_denom[dst]  (bit-identical ex)
//
// No segment-max: logits bounded ~7.2 -> exp <= ~1400, safe in fp32.
// No global atomics: per-line serialization on 8192 hot floats would cost
// tens of µs; non-atomic partial dump + reduce is ~17 MB of traffic instead.

#define NNODES 4096
#define NSEG   8192          // 2*NNODES
#define NEG_SLOPE 0.2f
#define EPB 32768            // edges per K3 block (1024 thr * 8 iters * 4/int4)

__global__ void k1_wvec(const float* __restrict__ W,
                        const float* __restrict__ att_src,
                        const float* __restrict__ att_dst,
                        float* __restrict__ wvs, float* __restrict__ wvd) {
    int f = threadIdx.x;                     // 256 threads, one per input feat
    const float* row = W + f * 128;
    float s = 0.f, d = 0.f;
    #pragma unroll 8
    for (int j = 0; j < 128; ++j) {
        float w = row[j];
        s += w * att_src[j];
        d += w * att_dst[j];
    }
    wvs[f] = s; wvd[f] = d;
}

__global__ void k2_logits(const float* __restrict__ x1, const float* __restrict__ x2,
                          const float* __restrict__ wvs, const float* __restrict__ wvd,
                          float* __restrict__ a_s, float* __restrict__ a_d) {
    int wave = blockIdx.x * 4 + (threadIdx.x >> 6);   // node id, 8192 waves
    int lane = threadIdx.x & 63;
    const float* xrow = (wave < NNODES) ? (x1 + (size_t)wave * 256)
                                        : (x2 + (size_t)(wave - NNODES) * 256);
    float4 xv  = ((const float4*)xrow)[lane];         // 256 floats = 64 float4
    float4 wsv = ((const float4*)wvs)[lane];
    float4 wdv = ((const float4*)wvd)[lane];
    float ps = xv.x*wsv.x + xv.y*wsv.y + xv.z*wsv.z + xv.w*wsv.w;
    float pd = xv.x*wdv.x + xv.y*wdv.y + xv.z*wdv.z + xv.w*wdv.w;
    #pragma unroll
    for (int o = 32; o > 0; o >>= 1) {
        ps += __shfl_down(ps, o);
        pd += __shfl_down(pd, o);
    }
    if (lane == 0) { a_s[wave] = ps; a_d[wave] = pd; }
}

__device__ __forceinline__ float edge_ex(const float* __restrict__ a_s,
                                         const float* __restrict__ a_d,
                                         int s, int d) {
    float e = a_s[s] + a_d[d];
    e = (e > 0.f) ? e : NEG_SLOPE * e;
    return __expf(e);
}

__global__ __launch_bounds__(1024) void k3_denom(
        const int* __restrict__ ei1, const int* __restrict__ ei2,
        const float* __restrict__ a_s, const float* __restrict__ a_d,
        float* __restrict__ partials, int E1, int g1_blocks) {
    __shared__ float ssum[NNODES];           // 16 KB: this block's graph half
    int t = threadIdx.x;
    for (int i = t; i < NNODES; i += 1024) ssum[i] = 0.f;
    __syncthreads();

    int b = blockIdx.x;
    const int *sp, *dp; int off, qbase;
    if (b < g1_blocks) { sp = ei1; dp = ei1 + E1; off = 0;      qbase = b * (EPB/4); }
    else               { sp = ei2; dp = ei2 + E1; off = NNODES; qbase = (b - g1_blocks) * (EPB/4); }
    const int4* s4 = (const int4*)sp;
    const int4* d4 = (const int4*)dp;

    #pragma unroll
    for (int k = 0; k < 8; ++k) {
        int q = qbase + (k << 10) + t;
        int4 sv = s4[q];
        int4 dv = d4[q];
        float e0 = edge_ex(a_s, a_d, sv.x + off, dv.x + off);
        float e1 = edge_ex(a_s, a_d, sv.y + off, dv.y + off);
        float e2 = edge_ex(a_s, a_d, sv.z + off, dv.z + off);
        float e3 = edge_ex(a_s, a_d, sv.w + off, dv.w + off);
        atomicAdd(&ssum[dv.x], e0);          // raw dst (per-graph half)
        atomicAdd(&ssum[dv.y], e1);
        atomicAdd(&ssum[dv.z], e2);
        atomicAdd(&ssum[dv.w], e3);
    }
    __syncthreads();
    float* pb = partials + (size_t)b * NNODES;
    for (int i = t; i < NNODES; i += 1024) pb[i] = ssum[i];
}

// partials[b][4096], b in [0, 2*g1_blocks). Stage A: 8 chunks per segment.
__global__ void k4a_reduce(const float* __restrict__ partials,
                           float* __restrict__ partials2, int g1_blocks) {
    int tid = blockIdx.x * blockDim.x + threadIdx.x;   // c*8192 + sg, c<8
    int c  = tid >> 13;
    int sg = tid & (NSEG - 1);
    int bpc = g1_blocks >> 3;                          // 32 blocks per chunk
    int b0 = ((sg < NNODES) ? 0 : g1_blocks) + c * bpc;
    int col = sg & (NNODES - 1);
    float s = 0.f;
    for (int j = 0; j < bpc; ++j)
        s += partials[(size_t)(b0 + j) * NNODES + col];
    partials2[tid] = s;
}

__global__ void k4b_inv(const float* __restrict__ partials2,
                        float* __restrict__ inv_denom) {
    int sg = blockIdx.x * blockDim.x + threadIdx.x;    // 8192
    float s = 0.f;
    #pragma unroll
    for (int c = 0; c < 8; ++c) s += partials2[c * NSEG + sg];
    inv_denom[sg] = 1.0f / s;
}

__global__ void k5_alpha(const int* __restrict__ ei1, const int* __restrict__ ei2,
                         const float* __restrict__ a_s, const float* __restrict__ a_d,
                         const float* __restrict__ inv_denom,
                         float* __restrict__ out, int E1) {
    int tid = blockIdx.x * blockDim.x + threadIdx.x;   // quad id over both graphs
    int nq1 = E1 >> 2;
    const int4 *s4, *d4; int off, q;
    if (tid < nq1) { s4 = (const int4*)ei1; d4 = (const int4*)(ei1 + E1); off = 0;      q = tid; }
    else           { s4 = (const int4*)ei2; d4 = (const int4*)(ei2 + E1); off = NNODES; q = tid - nq1; }
    int4 sv = s4[q];
    int4 dv = d4[q];
    float4 r;
    { int d = dv.x + off; r.x = edge_ex(a_s, a_d, sv.x + off, d) * inv_denom[d]; }
    { int d = dv.y + off; r.y = edge_ex(a_s, a_d, sv.y + off, d) * inv_denom[d]; }
    { int d = dv.z + off; r.z = edge_ex(a_s, a_d, sv.z + off, d) * inv_denom[d]; }
    { int d = dv.w + off; r.w = edge_ex(a_s, a_d, sv.w + off, d) * inv_denom[d]; }
    ((float4*)out)[tid] = r;
}

extern "C" void kernel_launch(void* const* d_in, const int* in_sizes, int n_in,
                              void* d_out, int out_size, void* d_ws, size_t ws_size,
                              hipStream_t stream) {
    const float* x1      = (const float*)d_in[0];
    const float* x2      = (const float*)d_in[1];
    const int*   ei1     = (const int*)d_in[2];
    const int*   ei2     = (const int*)d_in[3];
    const float* W       = (const float*)d_in[4];
    const float* att_src = (const float*)d_in[5];
    const float* att_dst = (const float*)d_in[6];
    float* out = (float*)d_out;

    const int E1 = in_sizes[2] / 2;          // 8388608 edges in graph 1

    // workspace layout (floats)
    float* wsf       = (float*)d_ws;
    float* wvs       = wsf;                  // 256
    float* wvd       = wsf + 256;            // 256
    float* a_s       = wsf + 512;            // 8192
    float* a_d       = wsf + 512 + NSEG;     // 8192
    float* inv_denom = wsf + 512 + 2*NSEG;   // 8192
    float* partials2 = wsf + 32768;          // 8*8192 = 65536
    float* partials  = wsf + 131072;         // 512*4096 = 2097152 (8 MB)

    hipLaunchKernelGGL(k1_wvec, dim3(1), dim3(256), 0, stream,
                       W, att_src, att_dst, wvs, wvd);
    hipLaunchKernelGGL(k2_logits, dim3(2 * NNODES / 4), dim3(256), 0, stream,
                       x1, x2, wvs, wvd, a_s, a_d);

    int g1_blocks = E1 / EPB;                // 256
    hipLaunchKernelGGL(k3_denom, dim3(2 * g1_blocks), dim3(1024), 0, stream,
                       ei1, ei2, a_s, a_d, partials, E1, g1_blocks);
    hipLaunchKernelGGL(k4a_reduce, dim3(8 * NSEG / 256), dim3(256), 0, stream,
                       partials, partials2, g1_blocks);
    hipLaunchKernelGGL(k4b_inv, dim3(NSEG / 256), dim3(256), 0, stream,
                       partials2, inv_denom);

    int nq = (2 * E1) / 4;                   // total edge quads
    hipLaunchKernelGGL(k5_alpha, dim3(nq / 256), dim3(256), 0, stream,
                       ei1, ei2, a_s, a_d, inv_denom, out, E1);
}

// Round 2
// 276.797 us; speedup vs baseline: 1.2150x; 1.2150x over previous
//
#include <hip/hip_runtime.h>

// GAT attention weights (heads=1) for two block-diagonal graphs.
// Output = softmax-by-dst of leakyrelu(a_s[src]+a_d[dst]) over N*N edges.
//
// R2 change: a_s / a_d / inv_denom for a graph half (16 KB each) are staged
// into LDS per block; per-edge gathers become ds_read_b32 instead of
// divergent global loads. R1 showed k3 at 8% HBM / 5% VALU / 0 LDS-conflict
// = TA address-throughput bound on 33.5M divergent gather lanes per kernel.
//
// No segment-max: logits bounded ~7.2 -> exp <= ~1400, safe in fp32.
// No global atomics: per-block LDS ssum + non-atomic partial dump + reduce.

#define NNODES 4096
#define NSEG   8192          // 2*NNODES
#define NEG_SLOPE 0.2f
#define EPB 32768            // edges per edge-kernel block (1024 thr * 8 * 4)

__global__ void k1_wvec(const float* __restrict__ W,
                        const float* __restrict__ att_src,
                        const float* __restrict__ att_dst,
                        float* __restrict__ wvs, float* __restrict__ wvd) {
    int f = threadIdx.x;                     // 256 threads, one per input feat
    const float* row = W + f * 128;
    float s = 0.f, d = 0.f;
    #pragma unroll 8
    for (int j = 0; j < 128; ++j) {
        float w = row[j];
        s += w * att_src[j];
        d += w * att_dst[j];
    }
    wvs[f] = s; wvd[f] = d;
}

__global__ void k2_logits(const float* __restrict__ x1, const float* __restrict__ x2,
                          const float* __restrict__ wvs, const float* __restrict__ wvd,
                          float* __restrict__ a_s, float* __restrict__ a_d) {
    int wave = blockIdx.x * 4 + (threadIdx.x >> 6);   // node id, 8192 waves
    int lane = threadIdx.x & 63;
    const float* xrow = (wave < NNODES) ? (x1 + (size_t)wave * 256)
                                        : (x2 + (size_t)(wave - NNODES) * 256);
    float4 xv  = ((const float4*)xrow)[lane];         // 256 floats = 64 float4
    float4 wsv = ((const float4*)wvs)[lane];
    float4 wdv = ((const float4*)wvd)[lane];
    float ps = xv.x*wsv.x + xv.y*wsv.y + xv.z*wsv.z + xv.w*wsv.w;
    float pd = xv.x*wdv.x + xv.y*wdv.y + xv.z*wdv.z + xv.w*wdv.w;
    #pragma unroll
    for (int o = 32; o > 0; o >>= 1) {
        ps += __shfl_down(ps, o);
        pd += __shfl_down(pd, o);
    }
    if (lane == 0) { a_s[wave] = ps; a_d[wave] = pd; }
}

__device__ __forceinline__ float lrelu_exp(float e) {
    e = (e > 0.f) ? e : NEG_SLOPE * e;
    return __expf(e);
}

__global__ __launch_bounds__(1024) void k3_denom(
        const int* __restrict__ ei1, const int* __restrict__ ei2,
        const float* __restrict__ a_s, const float* __restrict__ a_d,
        float* __restrict__ partials, int E1, int g1_blocks) {
    __shared__ float ssum[NNODES];           // 16 KB
    __shared__ float las[NNODES];            // 16 KB: a_s for this graph half
    __shared__ float lad[NNODES];            // 16 KB: a_d for this graph half
    int t = threadIdx.x;
    int b = blockIdx.x;
    const int *sp, *dp; int nodeoff, qbase;
    if (b < g1_blocks) { sp = ei1; dp = ei1 + E1; nodeoff = 0;      qbase = b * (EPB/4); }
    else               { sp = ei2; dp = ei2 + E1; nodeoff = NNODES; qbase = (b - g1_blocks) * (EPB/4); }

    // stage the half's logit vectors: 4096 floats = 1024 float4 each
    ((float4*)las)[t] = ((const float4*)(a_s + nodeoff))[t];
    ((float4*)lad)[t] = ((const float4*)(a_d + nodeoff))[t];
    for (int i = t; i < NNODES; i += 1024) ssum[i] = 0.f;
    __syncthreads();

    const int4* s4 = (const int4*)sp;
    const int4* d4 = (const int4*)dp;
    #pragma unroll
    for (int k = 0; k < 8; ++k) {
        int q = qbase + (k << 10) + t;
        int4 sv = s4[q];
        int4 dv = d4[q];
        float e0 = lrelu_exp(las[sv.x] + lad[dv.x]);
        float e1 = lrelu_exp(las[sv.y] + lad[dv.y]);
        float e2 = lrelu_exp(las[sv.z] + lad[dv.z]);
        float e3 = lrelu_exp(las[sv.w] + lad[dv.w]);
        atomicAdd(&ssum[dv.x], e0);
        atomicAdd(&ssum[dv.y], e1);
        atomicAdd(&ssum[dv.z], e2);
        atomicAdd(&ssum[dv.w], e3);
    }
    __syncthreads();
    float* pb = partials + (size_t)b * NNODES;
    for (int i = t; i < NNODES; i += 1024) pb[i] = ssum[i];
}

// partials[b][4096], b in [0, 2*g1_blocks). Stage A: 8 chunks per segment.
__global__ void k4a_reduce(const float* __restrict__ partials,
                           float* __restrict__ partials2, int g1_blocks) {
    int tid = blockIdx.x * blockDim.x + threadIdx.x;   // c*8192 + sg, c<8
    int c  = tid >> 13;
    int sg = tid & (NSEG - 1);
    int bpc = g1_blocks >> 3;                          // 32 blocks per chunk
    int b0 = ((sg < NNODES) ? 0 : g1_blocks) + c * bpc;
    int col = sg & (NNODES - 1);
    float s = 0.f;
    for (int j = 0; j < bpc; ++j)
        s += partials[(size_t)(b0 + j) * NNODES + col];
    partials2[tid] = s;
}

__global__ void k4b_inv(const float* __restrict__ partials2,
                        float* __restrict__ inv_denom) {
    int sg = blockIdx.x * blockDim.x + threadIdx.x;    // 8192
    float s = 0.f;
    #pragma unroll
    for (int c = 0; c < 8; ++c) s += partials2[c * NSEG + sg];
    inv_denom[sg] = 1.0f / s;
}

__global__ __launch_bounds__(1024) void k5_alpha(
        const int* __restrict__ ei1, const int* __restrict__ ei2,
        const float* __restrict__ a_s, const float* __restrict__ a_d,
        const float* __restrict__ inv_denom,
        float* __restrict__ out, int E1, int g1_blocks) {
    __shared__ float las[NNODES];            // 16 KB
    __shared__ float lad[NNODES];            // 16 KB
    __shared__ float linv[NNODES];           // 16 KB
    int t = threadIdx.x;
    int b = blockIdx.x;
    const int *sp, *dp; int nodeoff, qbase, outbase;
    if (b < g1_blocks) { sp = ei1; dp = ei1 + E1; nodeoff = 0;      qbase = b * (EPB/4); outbase = 0; }
    else               { sp = ei2; dp = ei2 + E1; nodeoff = NNODES; qbase = (b - g1_blocks) * (EPB/4); outbase = E1 / 4; }

    ((float4*)las)[t]  = ((const float4*)(a_s + nodeoff))[t];
    ((float4*)lad)[t]  = ((const float4*)(a_d + nodeoff))[t];
    ((float4*)linv)[t] = ((const float4*)(inv_denom + nodeoff))[t];
    __syncthreads();

    const int4* s4 = (const int4*)sp;
    const int4* d4 = (const int4*)dp;
    float4* out4 = (float4*)out;
    #pragma unroll
    for (int k = 0; k < 8; ++k) {
        int q = qbase + (k << 10) + t;
        int4 sv = s4[q];
        int4 dv = d4[q];
        float4 r;
        r.x = lrelu_exp(las[sv.x] + lad[dv.x]) * linv[dv.x];
        r.y = lrelu_exp(las[sv.y] + lad[dv.y]) * linv[dv.y];
        r.z = lrelu_exp(las[sv.z] + lad[dv.z]) * linv[dv.z];
        r.w = lrelu_exp(las[sv.w] + lad[dv.w]) * linv[dv.w];
        out4[outbase + q] = r;
    }
}

extern "C" void kernel_launch(void* const* d_in, const int* in_sizes, int n_in,
                              void* d_out, int out_size, void* d_ws, size_t ws_size,
                              hipStream_t stream) {
    const float* x1      = (const float*)d_in[0];
    const float* x2      = (const float*)d_in[1];
    const int*   ei1     = (const int*)d_in[2];
    const int*   ei2     = (const int*)d_in[3];
    const float* W       = (const float*)d_in[4];
    const float* att_src = (const float*)d_in[5];
    const float* att_dst = (const float*)d_in[6];
    float* out = (float*)d_out;

    const int E1 = in_sizes[2] / 2;          // 8388608 edges in graph 1

    // workspace layout (floats)
    float* wsf       = (float*)d_ws;
    float* wvs       = wsf;                  // 256
    float* wvd       = wsf + 256;            // 256
    float* a_s       = wsf + 512;            // 8192
    float* a_d       = wsf + 512 + NSEG;     // 8192
    float* inv_denom = wsf + 512 + 2*NSEG;   // 8192
    float* partials2 = wsf + 32768;          // 8*8192 = 65536
    float* partials  = wsf + 131072;         // 512*4096 = 2097152 (8 MB)

    hipLaunchKernelGGL(k1_wvec, dim3(1), dim3(256), 0, stream,
                       W, att_src, att_dst, wvs, wvd);
    hipLaunchKernelGGL(k2_logits, dim3(2 * NNODES / 4), dim3(256), 0, stream,
                       x1, x2, wvs, wvd, a_s, a_d);

    int g1_blocks = E1 / EPB;                // 256
    hipLaunchKernelGGL(k3_denom, dim3(2 * g1_blocks), dim3(1024), 0, stream,
                       ei1, ei2, a_s, a_d, partials, E1, g1_blocks);
    hipLaunchKernelGGL(k4a_reduce, dim3(8 * NSEG / 256), dim3(256), 0, stream,
                       partials, partials2, g1_blocks);
    hipLaunchKernelGGL(k4b_inv, dim3(NSEG / 256), dim3(256), 0, stream,
                       partials2, inv_denom);

    hipLaunchKernelGGL(k5_alpha, dim3(2 * g1_blocks), dim3(1024), 0, stream,
                       ei1, ei2, a_s, a_d, inv_denom, out, E1, g1_blocks);
}